// Round 1
// baseline (18725.615 us; speedup 1.0000x reference)
//
#include <hip/hip_runtime.h>
#include <hip/hip_fp16.h>
#include <cstdint>

typedef _Float16 f16x8 __attribute__((ext_vector_type(8)));
typedef _Float16 half2_t __attribute__((ext_vector_type(2)));
typedef float f32x4 __attribute__((ext_vector_type(4)));

// Problem sizes
// B=64, T=1024, IN=256, HID=256, gates packed as col c = s*512 + u_local*4 + g
// (s = which half-WG owns the unit, g: 0=i,1=f,2=o,3=c), u = c>>2.

// Workspace layout (bytes)
#define XG_OFF    0ULL
#define XG_BYTES  134217728ULL   // 65536 rows x 1024 cols x fp16
#define AP_OFF    (XG_OFF + XG_BYTES)
#define AP_BYTES  33554432ULL    // A fragments: 4096 mtiles x 8 kk x 64 lanes x 8 f16
#define BP_OFF    (AP_OFF + AP_BYTES)
#define BP_BYTES  524288ULL      // B fragments: 64 ntiles x 8 kk x 64 lanes x 8 f16
#define WHP_OFF   (BP_OFF + BP_BYTES)
#define WHP_BYTES 524288ULL      // recurrent weights packed: [2][128][512] u32 (half2)
#define BIAS_OFF  (WHP_OFF + WHP_BYTES)
#define BIAS_BYTES 4096ULL       // bias_eff[1024] f32
#define HBUF_OFF  (BIAS_OFF + BIAS_BYTES)
#define HBUF_BYTES 131072ULL     // [2 parity][64 b][2 s][128] f32
#define FLAG_OFF  (HBUF_OFF + HBUF_BYTES)
#define FLAG_BYTES 512ULL        // [64 b][2 s] u32

__device__ inline half2_t u2h2(uint32_t v) {
    union { uint32_t u; half2_t h; } c; c.u = v; return c.h;
}

// ---------------- Phase 0: pack recurrent weights + B fragments + bias ----------------
__global__ void pack_weights(const float* __restrict__ Wi, const float* __restrict__ Wf,
                             const float* __restrict__ Wo, const float* __restrict__ Wc,
                             const float* __restrict__ bi, const float* __restrict__ bf,
                             const float* __restrict__ bo, const float* __restrict__ bc,
                             uint32_t* __restrict__ Whp, __half* __restrict__ Bp,
                             float* __restrict__ bias_eff)
{
    int tidg = blockIdx.x * blockDim.x + threadIdx.x;
    if (tidg < 131072) {
        // Whp[(s*128 + kp)*512 + tid] ; thread tid owns col (u_local=tid>>2, g=tid&3)
        int tid = tidg & 511;
        int kp  = (tidg >> 9) & 127;
        int s   = tidg >> 16;
        int u = s * 128 + (tid >> 2);
        int g = tid & 3;
        const float* W = (g == 0) ? Wi : (g == 1) ? Wf : (g == 2) ? Wo : Wc;
        // local kp order: [0,64) = own half units, [64,128) = peer half
        int kpg = (kp < 64) ? (s * 64 + kp) : ((1 - s) * 64 + (kp - 64));
        int k2 = kpg * 2;
        union { uint32_t u32; __half h[2]; } pk;
        pk.h[0] = __float2half(W[k2 * 256 + u]);        // h-part rows 0..255
        pk.h[1] = __float2half(W[(k2 + 1) * 256 + u]);
        Whp[tidg] = pk.u32;
    } else if (tidg < 131072 + 262144) {
        // Bp[((n*8+kk)*64+l)*8+i] = Wx_eff[k = kk*32+(l>>4)*8+i][c = n*16+(l&15)]
        int beta = tidg - 131072;
        int i = beta & 7;
        int l = (beta >> 3) & 63;
        int kk = (beta >> 9) & 7;
        int n = beta >> 12;
        int c = n * 16 + (l & 15);
        int u = c >> 2, g = c & 3;
        int k = kk * 32 + (l >> 4) * 8 + i;
        const float* W = (g == 0) ? Wi : (g == 1) ? Wf : (g == 2) ? Wo : Wc;
        Bp[beta] = __float2half(W[(256 + k) * 256 + u]);  // x-part rows 256..511
    } else if (tidg < 131072 + 262144 + 1024) {
        int c = tidg - (131072 + 262144);
        int g = c & 3;
        const float* bb = (g == 0) ? bi : (g == 1) ? bf : (g == 2) ? bo : bc;
        bias_eff[c] = bb[c >> 2];
    }
}

// ---------------- Phase 0b: pack x into A fragments (fp16, mfma layout) ----------------
__global__ void pack_a(const float* __restrict__ x, __half* __restrict__ Ap)
{
    int t = blockIdx.x * blockDim.x + threadIdx.x;   // [0, 2097152)
    int l  = t & 63;
    int kk = (t >> 6) & 7;
    int m  = t >> 9;
    int row = m * 16 + (l & 15);
    int k0  = kk * 32 + (l >> 4) * 8;
    const float* src = x + (size_t)row * 256 + k0;
    f16x8 v;
#pragma unroll
    for (int i = 0; i < 8; ++i) v[i] = (_Float16)src[i];
    *reinterpret_cast<f16x8*>(Ap + (size_t)t * 8) = v;
}

// ---------------- Phase 1: xg = x @ Wx + bias  (MFMA f16, fp32 accum, fp16 out) --------
__global__ __launch_bounds__(256) void gemm_xg(const __half* __restrict__ Ap,
                                               const __half* __restrict__ Bp,
                                               const float* __restrict__ bias_eff,
                                               __half* __restrict__ xg)
{
    int wave = threadIdx.x >> 6;
    int lane = threadIdx.x & 63;
    int mtile = blockIdx.x * 4 + wave;      // 4096 mtiles of 16 rows
    int ntbase = blockIdx.y * 16;           // 4 N-blocks of 16 ntiles (16 cols each)

    f16x8 a[8];
#pragma unroll
    for (int kk = 0; kk < 8; ++kk)
        a[kk] = *reinterpret_cast<const f16x8*>(Ap + ((size_t)(mtile * 8 + kk) * 64 + lane) * 8);

    int col_lo = lane & 15;
    int rgrp = lane >> 4;
#pragma unroll 1
    for (int j = 0; j < 16; ++j) {
        int nt = ntbase + j;
        float bb = bias_eff[nt * 16 + col_lo];
        f32x4 acc = {bb, bb, bb, bb};
#pragma unroll
        for (int kk = 0; kk < 8; ++kk) {
            f16x8 bfr = *reinterpret_cast<const f16x8*>(Bp + ((size_t)(nt * 8 + kk) * 64 + lane) * 8);
            acc = __builtin_amdgcn_mfma_f32_16x16x32_f16(a[kk], bfr, acc, 0, 0, 0);
        }
        // C/D layout (verified, dtype-independent): col=lane&15, row=(lane>>4)*4+reg
#pragma unroll
        for (int r = 0; r < 4; ++r) {
            int row = mtile * 16 + rgrp * 4 + r;
            xg[(size_t)row * 1024 + nt * 16 + col_lo] = __float2half(acc[r]);
        }
    }
}

// ---------------- Phase 2: sequential recurrence --------------------------------------
// 128 WGs: WG (b = blk&63, s = blk>>6). ids b and 64+b are congruent mod 8 -> likely
// same XCD (perf only; correctness uses agent-scope atomics). 512 threads: thread owns
// gate column (u_local=tid>>2, g=tid&3) with its 256 recurrent weights in 128 VGPRs.
__global__ __launch_bounds__(512, 2) void lstm_rec(
    const __half* __restrict__ xg,
    const uint32_t* __restrict__ Whp,
    float* __restrict__ out,
    float* hbuf,
    uint32_t* flags)
{
    const int blk = blockIdx.x;
    const int s = blk >> 6;
    const int b = blk & 63;
    const int tid = threadIdx.x;
    const int ul = tid >> 2, g = tid & 3;
    const int u = s * 128 + ul;

    // register-resident recurrent weights (packed fp16 pairs)
    uint32_t w[128];
#pragma unroll
    for (int kp = 0; kp < 128; ++kp)
        w[kp] = Whp[(s * 128 + kp) * 512 + tid];

    __shared__ uint32_t h2[128];       // full h (256 units) as packed fp16 pairs
    __shared__ float gates[4][128];
    if (tid < 128) h2[tid] = 0u;
    __syncthreads();

    float c_state = 0.f;
    const __half* xptr = xg + ((size_t)b * 1024) * 1024 + s * 512 + tid;
    uint32_t* myflag   = flags + (b * 2 + s);
    uint32_t* peerflag = flags + (b * 2 + (1 - s));
    float* hb_w = hbuf + (size_t)(b * 2 + s) * 128;
    float* hb_r = hbuf + (size_t)(b * 2 + (1 - s)) * 128;
    const int own_base = s * 64, peer_base = (1 - s) * 64;
    __half* h2h = reinterpret_cast<__half*>(h2);

    float xv = (float)xptr[0];   // software-pipelined xg load (1 step ahead)

    for (int t = 0; t < 1024; ++t) {
        int tn = (t < 1023) ? (t + 1) : 1023;
        float xv_next = (float)xptr[(size_t)tn * 1024];

        // dot over OWN half of h first (hides peer sync latency)
        float a0 = 0.f, a1 = 0.f, a2 = 0.f, a3 = 0.f;
#pragma unroll
        for (int kp = 0; kp < 64; kp += 4) {
            a0 = __builtin_amdgcn_fdot2(u2h2(w[kp + 0]), u2h2(h2[own_base + kp + 0]), a0, false);
            a1 = __builtin_amdgcn_fdot2(u2h2(w[kp + 1]), u2h2(h2[own_base + kp + 1]), a1, false);
            a2 = __builtin_amdgcn_fdot2(u2h2(w[kp + 2]), u2h2(h2[own_base + kp + 2]), a2, false);
            a3 = __builtin_amdgcn_fdot2(u2h2(w[kp + 3]), u2h2(h2[own_base + kp + 3]), a3, false);
        }

        if (t > 0) {
            if (tid == 0) {
                while (__hip_atomic_load(peerflag, __ATOMIC_ACQUIRE, __HIP_MEMORY_SCOPE_AGENT) < (uint32_t)t) { }
            }
            __syncthreads();
            if (tid < 128) {
                float hv = __hip_atomic_load(hb_r + (size_t)((t - 1) & 1) * 16384 + tid,
                                             __ATOMIC_RELAXED, __HIP_MEMORY_SCOPE_AGENT);
                h2h[peer_base * 2 + tid] = __float2half(hv);
            }
            __syncthreads();
        }

        // dot over PEER half
#pragma unroll
        for (int kp = 64; kp < 128; kp += 4) {
            a0 = __builtin_amdgcn_fdot2(u2h2(w[kp + 0]), u2h2(h2[peer_base + kp - 64 + 0]), a0, false);
            a1 = __builtin_amdgcn_fdot2(u2h2(w[kp + 1]), u2h2(h2[peer_base + kp - 64 + 1]), a1, false);
            a2 = __builtin_amdgcn_fdot2(u2h2(w[kp + 2]), u2h2(h2[peer_base + kp - 64 + 2]), a2, false);
            a3 = __builtin_amdgcn_fdot2(u2h2(w[kp + 3]), u2h2(h2[peer_base + kp - 64 + 3]), a3, false);
        }

        float pre = ((a0 + a1) + (a2 + a3)) + xv;
        float gv;
        if (g == 3) {                       // candidate: tanh
            float e = __expf(-2.f * pre);
            gv = (1.f - e) / (1.f + e);
        } else {                            // i,f,o: sigmoid
            gv = 1.f / (1.f + __expf(-pre));
        }
        gates[g][ul] = gv;
        __syncthreads();

        float iv = gates[0][ul], fv = gates[1][ul], ov = gates[2][ul], cg = gates[3][ul];
        c_state = fv * c_state + iv * cg;   // all 4 threads keep redundant c (no divergence)
        float e2 = __expf(-2.f * c_state);
        float th = (1.f - e2) / (1.f + e2);
        float hv = ov * th;

        if (g == 0)      out[((size_t)t * 64 + b) * 256 + u] = hv;
        else if (g == 1) __hip_atomic_store(hb_w + (size_t)(t & 1) * 16384 + ul, hv,
                                            __ATOMIC_RELAXED, __HIP_MEMORY_SCOPE_AGENT);
        else if (g == 2) h2h[u] = __float2half(hv);

        if (g == 1) __threadfence();        // order hbuf stores before flag
        __syncthreads();
        if (tid == 0)
            __hip_atomic_store(myflag, (uint32_t)(t + 1), __ATOMIC_RELEASE, __HIP_MEMORY_SCOPE_AGENT);

        xv = xv_next;
    }
}

// ---------------- launch ----------------
extern "C" void kernel_launch(void* const* d_in, const int* in_sizes, int n_in,
                              void* d_out, int out_size, void* d_ws, size_t ws_size,
                              hipStream_t stream)
{
    const float* x  = (const float*)d_in[0];
    const float* Wi = (const float*)d_in[1];
    const float* bi = (const float*)d_in[2];
    const float* Wf = (const float*)d_in[3];
    const float* bf = (const float*)d_in[4];
    const float* Wo = (const float*)d_in[5];
    const float* bo = (const float*)d_in[6];
    const float* Wc = (const float*)d_in[7];
    const float* bc = (const float*)d_in[8];

    char* ws = (char*)d_ws;
    __half*  xg       = (__half*)(ws + XG_OFF);
    __half*  Ap       = (__half*)(ws + AP_OFF);
    __half*  Bp       = (__half*)(ws + BP_OFF);
    uint32_t* Whp     = (uint32_t*)(ws + WHP_OFF);
    float*   bias_eff = (float*)(ws + BIAS_OFF);
    float*   hbuf     = (float*)(ws + HBUF_OFF);
    uint32_t* flags   = (uint32_t*)(ws + FLAG_OFF);

    hipMemsetAsync(flags, 0, FLAG_BYTES, stream);
    pack_weights<<<1540, 256, 0, stream>>>(Wi, Wf, Wo, Wc, bi, bf, bo, bc, Whp, Bp, bias_eff);
    pack_a<<<8192, 256, 0, stream>>>(x, Ap);
    gemm_xg<<<dim3(1024, 4), 256, 0, stream>>>(Ap, Bp, bias_eff, xg);
    lstm_rec<<<128, 512, 0, stream>>>(xg, Whp, (float*)d_out, hbuf, flags);
}

// Round 2
// 1914.699 us; speedup vs baseline: 9.7799x; 9.7799x over previous
//
#include <hip/hip_runtime.h>
#include <hip/hip_fp16.h>
#include <cstdint>

typedef _Float16 f16x8 __attribute__((ext_vector_type(8)));
typedef _Float16 half2_t __attribute__((ext_vector_type(2)));
typedef float f32x4 __attribute__((ext_vector_type(4)));
typedef uint32_t u32x4 __attribute__((ext_vector_type(4)));

// Sizes: B=64, T=1024, IN=256, HID=256. Packed gate column c in [0,1024):
// unit u = c>>2, gate g = c&3 (g: 0=i,1=f,2=o,3=c).

// Workspace layout (bytes)
#define XG_OFF    0ULL
#define XG_BYTES  134217728ULL   // xg[b*1024+t][c] fp16: 65536 x 1024
#define AP_OFF    (XG_OFF + XG_BYTES)
#define AP_BYTES  33554432ULL    // A fragments
#define BP_OFF    (AP_OFF + AP_BYTES)
#define BP_BYTES  524288ULL      // B fragments
#define WHP_OFF   (BP_OFF + BP_BYTES)
#define WHP_BYTES 524288ULL      // Whp[kp][c]: 128 x 1024 u32 (f16 pair per kp)
#define BIAS_OFF  (WHP_OFF + WHP_BYTES)

// Recurrent-weight split: kp in [0,112) -> 28 u32x4 per col in VGPRs,
// kp=112 -> 1 scalar u32 per col, kp in [113,128) -> LDS (15 x 1024 u32 = 60KB).
#define KRQ 28
#define KLB 113
#define KL  15

__device__ inline half2_t u2h2(uint32_t v) {
    union { uint32_t u; half2_t h; } c; c.u = v; return c.h;
}

#define QB(v, pat) __int_as_float(__builtin_amdgcn_ds_swizzle(__float_as_int(v), (pat)))

// ---------------- Phase 0: pack recurrent weights + B fragments + bias ----------------
__global__ void pack_weights(const float* __restrict__ Wi, const float* __restrict__ Wf,
                             const float* __restrict__ Wo, const float* __restrict__ Wc,
                             const float* __restrict__ bi, const float* __restrict__ bf,
                             const float* __restrict__ bo, const float* __restrict__ bc,
                             uint32_t* __restrict__ Whp, __half* __restrict__ Bp,
                             float* __restrict__ bias_eff)
{
    int tidg = blockIdx.x * blockDim.x + threadIdx.x;
    if (tidg < 131072) {
        // Whp[kp*1024 + c] = pack(Wg[2kp][u], Wg[2kp+1][u]), h-part rows [0,256)
        int c  = tidg & 1023;
        int kp = tidg >> 10;
        int u = c >> 2, g = c & 3;
        const float* W = (g == 0) ? Wi : (g == 1) ? Wf : (g == 2) ? Wo : Wc;
        union { uint32_t u32; __half h[2]; } pk;
        pk.h[0] = __float2half(W[(2 * kp) * 256 + u]);
        pk.h[1] = __float2half(W[(2 * kp + 1) * 256 + u]);
        Whp[tidg] = pk.u32;
    } else if (tidg < 131072 + 262144) {
        // Bp[((n*8+kk)*64+l)*8+i] = Wx_eff[k = kk*32+(l>>4)*8+i][c = n*16+(l&15)]
        int beta = tidg - 131072;
        int i = beta & 7;
        int l = (beta >> 3) & 63;
        int kk = (beta >> 9) & 7;
        int n = beta >> 12;
        int c = n * 16 + (l & 15);
        int u = c >> 2, g = c & 3;
        int k = kk * 32 + (l >> 4) * 8 + i;
        const float* W = (g == 0) ? Wi : (g == 1) ? Wf : (g == 2) ? Wo : Wc;
        Bp[beta] = __float2half(W[(256 + k) * 256 + u]);  // x-part rows 256..511
    } else if (tidg < 131072 + 262144 + 1024) {
        int c = tidg - (131072 + 262144);
        int g = c & 3;
        const float* bb = (g == 0) ? bi : (g == 1) ? bf : (g == 2) ? bo : bc;
        bias_eff[c] = bb[c >> 2];
    }
}

// ---------------- Phase 0b: pack x into A fragments ----------------
__global__ void pack_a(const float* __restrict__ x, __half* __restrict__ Ap)
{
    int t = blockIdx.x * blockDim.x + threadIdx.x;   // [0, 2097152)
    int l  = t & 63;
    int kk = (t >> 6) & 7;
    int m  = t >> 9;
    int row = m * 16 + (l & 15);
    int k0  = kk * 32 + (l >> 4) * 8;
    const float* src = x + (size_t)row * 256 + k0;
    f16x8 v;
#pragma unroll
    for (int i = 0; i < 8; ++i) v[i] = (_Float16)src[i];
    *reinterpret_cast<f16x8*>(Ap + (size_t)t * 8) = v;
}

// ---------------- Phase 1: xg = x @ Wx + bias ----------------
__global__ __launch_bounds__(256) void gemm_xg(const __half* __restrict__ Ap,
                                               const __half* __restrict__ Bp,
                                               const float* __restrict__ bias_eff,
                                               __half* __restrict__ xg)
{
    int wave = threadIdx.x >> 6;
    int lane = threadIdx.x & 63;
    int mtile = blockIdx.x * 4 + wave;
    int ntbase = blockIdx.y * 16;

    f16x8 a[8];
#pragma unroll
    for (int kk = 0; kk < 8; ++kk)
        a[kk] = *reinterpret_cast<const f16x8*>(Ap + ((size_t)(mtile * 8 + kk) * 64 + lane) * 8);

    int col_lo = lane & 15;
    int rgrp = lane >> 4;
#pragma unroll 1
    for (int j = 0; j < 16; ++j) {
        int nt = ntbase + j;
        float bb = bias_eff[nt * 16 + col_lo];
        f32x4 acc = {bb, bb, bb, bb};
#pragma unroll
        for (int kk = 0; kk < 8; ++kk) {
            f16x8 bfr = *reinterpret_cast<const f16x8*>(Bp + ((size_t)(nt * 8 + kk) * 64 + lane) * 8);
            acc = __builtin_amdgcn_mfma_f32_16x16x32_f16(a[kk], bfr, acc, 0, 0, 0);
        }
#pragma unroll
        for (int r = 0; r < 4; ++r) {
            int row = mtile * 16 + rgrp * 4 + r;
            xg[(size_t)row * 1024 + nt * 16 + col_lo] = __float2half(acc[r]);
        }
    }
}

// ---------------- Phase 2: sequential recurrence, ONE WG per batch ----------------
// 64 WGs x 512 threads. Thread tid owns gate columns c0=tid (u0=tid>>2) and
// c1=512+tid (u1=128+(tid>>2)), same gate g=tid&3. Recurrent weights:
// 2 x (28 u32x4 + 1 u32) in VGPRs + 2 x 15 u32 in LDS. h double-buffered in LDS,
// one __syncthreads per step. Gate exchange via ds_swizzle quad broadcast.
__global__ __launch_bounds__(512, 2) void lstm_rec(
    const __half* __restrict__ xg,
    const uint32_t* __restrict__ Whp,
    float* __restrict__ out)
{
    const int b = blockIdx.x;
    const int tid = threadIdx.x;
    const int g = tid & 3;
    const int ul = tid >> 2;          // u0 = ul, u1 = 128 + ul

    __shared__ uint32_t Wl[KL][1024];             // 60 KB
    __shared__ alignas(16) uint32_t h2[2][128];   // 1 KB, f16-pair packed h

    // cooperative LDS fill: Whp rows [113,128) are flat [113*1024, 128*1024)
    {
        const uint32_t* src = Whp + KLB * 1024;
        for (int i = tid; i < KL * 1024; i += 512) ((uint32_t*)Wl)[i] = src[i];
        if (tid < 128) { h2[0][tid] = 0u; h2[1][tid] = 0u; }
    }

    // register-resident weights (statically indexed ext-vectors)
    u32x4 w0[KRQ], w1[KRQ];
#pragma unroll
    for (int q = 0; q < KRQ; ++q) {
#pragma unroll
        for (int i = 0; i < 4; ++i) {
            w0[q][i] = Whp[(q * 4 + i) * 1024 + tid];
            w1[q][i] = Whp[(q * 4 + i) * 1024 + 512 + tid];
        }
    }
    uint32_t w0e = Whp[112 * 1024 + tid];
    uint32_t w1e = Whp[112 * 1024 + 512 + tid];
    __syncthreads();

    // branchless activation constants (uniform per thread, hoisted)
    const float kAct = (g == 3) ? 2.88539008f : -1.44269504f;  // tanh : sigmoid
    const float aAct = (g == 3) ? -2.0f : 1.0f;
    const float bAct = (g == 3) ? 1.0f : 0.0f;

    float c0s = 0.f, c1s = 0.f;
    const __half* xrow = xg + (size_t)b * 1024 * 1024;

    for (int t = 0; t < 1024; ++t) {
        const uint32_t* hr = h2[t & 1];
        // x pre-activations: issued early, consumed ~1200cy later (latency hidden)
        float xv0 = (float)xrow[t * 1024 + tid];
        float xv1 = (float)xrow[t * 1024 + 512 + tid];

        float a00 = 0.f, a01 = 0.f, a10 = 0.f, a11 = 0.f;
#pragma unroll
        for (int q = 0; q < KRQ; ++q) {
            u32x4 hq = *reinterpret_cast<const u32x4*>(&hr[q * 4]);   // broadcast b128
            a00 = __builtin_amdgcn_fdot2(u2h2(w0[q][0]), u2h2(hq[0]), a00, false);
            a10 = __builtin_amdgcn_fdot2(u2h2(w1[q][0]), u2h2(hq[0]), a10, false);
            a01 = __builtin_amdgcn_fdot2(u2h2(w0[q][1]), u2h2(hq[1]), a01, false);
            a11 = __builtin_amdgcn_fdot2(u2h2(w1[q][1]), u2h2(hq[1]), a11, false);
            a00 = __builtin_amdgcn_fdot2(u2h2(w0[q][2]), u2h2(hq[2]), a00, false);
            a10 = __builtin_amdgcn_fdot2(u2h2(w1[q][2]), u2h2(hq[2]), a10, false);
            a01 = __builtin_amdgcn_fdot2(u2h2(w0[q][3]), u2h2(hq[3]), a01, false);
            a11 = __builtin_amdgcn_fdot2(u2h2(w1[q][3]), u2h2(hq[3]), a11, false);
        }
        // tail: kp 112..127 via 4 broadcast quads
        {
            u32x4 hA = *reinterpret_cast<const u32x4*>(&hr[112]);
            u32x4 hB = *reinterpret_cast<const u32x4*>(&hr[116]);
            u32x4 hC = *reinterpret_cast<const u32x4*>(&hr[120]);
            u32x4 hD = *reinterpret_cast<const u32x4*>(&hr[124]);
            a00 = __builtin_amdgcn_fdot2(u2h2(w0e), u2h2(hA[0]), a00, false);
            a10 = __builtin_amdgcn_fdot2(u2h2(w1e), u2h2(hA[0]), a10, false);
#define LPART(J, HV) \
            a01 = __builtin_amdgcn_fdot2(u2h2(Wl[(J)][tid]), u2h2(HV), a01, false); \
            a11 = __builtin_amdgcn_fdot2(u2h2(Wl[(J)][512 + tid]), u2h2(HV), a11, false);
            LPART(0, hA[1]) LPART(1, hA[2]) LPART(2, hA[3])
            LPART(3, hB[0]) LPART(4, hB[1]) LPART(5, hB[2]) LPART(6, hB[3])
            LPART(7, hC[0]) LPART(8, hC[1]) LPART(9, hC[2]) LPART(10, hC[3])
            LPART(11, hD[0]) LPART(12, hD[1]) LPART(13, hD[2]) LPART(14, hD[3])
#undef LPART
        }

        float pre0 = (a00 + a01) + xv0;
        float pre1 = (a10 + a11) + xv1;

        // gv = aAct * rcp(1 + exp2(kAct*pre)) + bAct  (sigmoid or tanh, branchless)
        float r0 = __builtin_amdgcn_rcpf(1.f + __builtin_amdgcn_exp2f(kAct * pre0));
        float r1 = __builtin_amdgcn_rcpf(1.f + __builtin_amdgcn_exp2f(kAct * pre1));
        float gv0 = fmaf(aAct, r0, bAct);
        float gv1 = fmaf(aAct, r1, bAct);

        // quad gate exchange (lanes 4u..4u+3 hold i,f,o,c of unit u)
        float i0 = QB(gv0, 0x8000), f0 = QB(gv0, 0x8055), o0 = QB(gv0, 0x80AA), q0 = QB(gv0, 0x80FF);
        float i1 = QB(gv1, 0x8000), f1 = QB(gv1, 0x8055), o1 = QB(gv1, 0x80AA), q1 = QB(gv1, 0x80FF);

        c0s = fmaf(f0, c0s, i0 * q0);
        c1s = fmaf(f1, c1s, i1 * q1);
        // tanh(c) = 1 - 2*rcp(1+exp2(2.885*c))
        float t0 = fmaf(-2.f, __builtin_amdgcn_rcpf(1.f + __builtin_amdgcn_exp2f(2.88539008f * c0s)), 1.f);
        float t1 = fmaf(-2.f, __builtin_amdgcn_rcpf(1.f + __builtin_amdgcn_exp2f(2.88539008f * c1s)), 1.f);
        float h0 = o0 * t0;
        float h1 = o1 * t1;

        __half* hw = reinterpret_cast<__half*>(h2[(t + 1) & 1]);
        if (g == 0) {
            hw[ul] = __float2half(h0);
            hw[128 + ul] = __float2half(h1);
        } else if (g == 1) {
            float* orow = out + ((size_t)t * 64 + b) * 256;
            orow[ul] = h0;
            orow[128 + ul] = h1;
        }
        __syncthreads();
    }
}

// ---------------- launch ----------------
extern "C" void kernel_launch(void* const* d_in, const int* in_sizes, int n_in,
                              void* d_out, int out_size, void* d_ws, size_t ws_size,
                              hipStream_t stream)
{
    const float* x  = (const float*)d_in[0];
    const float* Wi = (const float*)d_in[1];
    const float* bi = (const float*)d_in[2];
    const float* Wf = (const float*)d_in[3];
    const float* bf = (const float*)d_in[4];
    const float* Wo = (const float*)d_in[5];
    const float* bo = (const float*)d_in[6];
    const float* Wc = (const float*)d_in[7];
    const float* bc = (const float*)d_in[8];

    char* ws = (char*)d_ws;
    __half*   xg       = (__half*)(ws + XG_OFF);
    __half*   Ap       = (__half*)(ws + AP_OFF);
    __half*   Bp       = (__half*)(ws + BP_OFF);
    uint32_t* Whp      = (uint32_t*)(ws + WHP_OFF);
    float*    bias_eff = (float*)(ws + BIAS_OFF);

    pack_weights<<<1540, 256, 0, stream>>>(Wi, Wf, Wo, Wc, bi, bf, bo, bc, Whp, Bp, bias_eff);
    pack_a<<<8192, 256, 0, stream>>>(x, Ap);
    gemm_xg<<<dim3(1024, 4), 256, 0, stream>>>(Ap, Bp, bias_eff, xg);
    lstm_rec<<<64, 512, 0, stream>>>(xg, Whp, (float*)d_out);
}